// Round 1
// 443.411 us; speedup vs baseline: 1.0086x; 1.0086x over previous
//
#include <hip/hip_runtime.h>
#include <hip/hip_bf16.h>

// Shapes fixed by the reference: B=32, T=2048, C=1024, HS=64
#define Bn 32
#define Tn 2048
#define Cn 1024
#define HSn 64

typedef __attribute__((ext_vector_type(8))) short short8;   // 8 bf16 (4 VGPRs) MFMA A/B frag
typedef __attribute__((ext_vector_type(4))) float floatx4;  // MFMA C/D frag

#if __has_builtin(__builtin_amdgcn_exp2f)
#define EXP2F __builtin_amdgcn_exp2f
#else
#define EXP2F exp2f
#endif

// fp32 -> bf16 round-to-nearest-even
static __device__ __forceinline__ short f2bf(float f) {
    union { float f; unsigned u; } v; v.f = f;
    unsigned r = v.u + 0x7FFFu + ((v.u >> 16) & 1u);
    return (short)(r >> 16);
}

// packed fp32x2 -> bf16x2 (RNE), single VALU op
static __device__ __forceinline__ unsigned cvt_pk_bf16(float lo, float hi) {
    unsigned u;
    asm("v_cvt_pk_bf16_f32 %0, %1, %2" : "=v"(u) : "v"(lo), "v"(hi));
    return u;
}

// async global->LDS, 16B per lane.  HW: dst = wave-uniform base + lane*16;
// src is per-lane.  Completion tracked by vmcnt (drained at __syncthreads).
static __device__ __forceinline__ void async16(const void* g, void* l) {
    __builtin_amdgcn_global_load_lds((const __attribute__((address_space(1))) void*)g,
                                     (__attribute__((address_space(3))) void*)l,
                                     16, 0, 0);
}

// ---------------------------------------------------------------------------
// Kernel 1: swizzle W (fp32 [1024,64] x3) into bf16 MFMA-B-fragment order.
// Combined cols: [0,64)=Wq, [64,128)=Wk, [128,192)=Wv.
// ---------------------------------------------------------------------------
__global__ __launch_bounds__(256) void swz_w(const float* __restrict__ Wk,
                                             const float* __restrict__ Wq,
                                             const float* __restrict__ Wv,
                                             short* __restrict__ wswz) {
    int e = blockIdx.x * 256 + threadIdx.x;   // 0 .. 196607
    int j    = e & 7;
    int lane = (e >> 3) & 63;
    int grp  = e >> 9;            // kc*12 + nt
    int nt   = grp % 12;
    int kc   = grp / 12;
    int q = lane >> 4, m = lane & 15;
    int k = kc * 32 + q * 8 + j;
    int n = nt * 16 + m;
    const float* W = (n < 64) ? Wq : ((n < 128) ? Wk : Wv);
    wswz[e] = f2bf(W[k * 64 + (n & 63)]);
}

// ---------------------------------------------------------------------------
// Kernel 2: fused QKV projection, LDS double-buffer pipeline (m97 pattern).
// out[M=65536, N=192] = x[M,1024] @ Wqkv.  Block = 128 rows, BK=32,
// grid 512 = 2 blocks/CU (LDS 2x28KB).
// This round: A-fragment fp32->bf16 repack via v_cvt_pk_bf16_f32 (8 VALU ops
// per wave-iter instead of ~64 integer-RNE ops).
// ---------------------------------------------------------------------------
__global__ __launch_bounds__(256, 2) void qkv_gemm(const float* __restrict__ x,
                                                   const short* __restrict__ wswz,
                                                   short* __restrict__ qb,
                                                   short* __restrict__ kb,
                                                   short* __restrict__ vt) {
    __shared__ __align__(16) char lds[2][28 * 1024];   // [buf][A 16KB | B 12KB]

    int tid = threadIdx.x;
    int w = tid >> 6, l = tid & 63;
    int quad = l >> 4, m = l & 15;
    int r0 = blockIdx.x * 128;

    floatx4 acc[2][12];
#pragma unroll
    for (int r = 0; r < 2; r++)
#pragma unroll
        for (int nt = 0; nt < 12; nt++) acc[r][nt] = (floatx4)(0.0f);

    // ---- stage chunk kc into buffer bsel (wave w: 4 A + 3 B instrs)
    auto stage = [&](int kc, int bsel) {
        char* ab = &lds[bsel][0];
        char* bb = &lds[bsel][16 * 1024];
        int srow = l & 15, sc = l >> 4;                // staging lane -> (row, chunk)
#pragma unroll
        for (int i = 0; i < 2; i++) {
            int rt = 2 * w + i;
            const float* rbase = x + (size_t)(r0 + rt * 16 + srow) * Cn + kc * 32;
#pragma unroll
            for (int h = 0; h < 2; h++)                // 64B half of the 128B row-chunk
                async16(rbase + h * 16 + sc * 4,
                        ab + rt * 2048 + h * 1024 + l * 16);
        }
#pragma unroll
        for (int i = 0; i < 3; i++) {
            int nt = 3 * w + i;
            const short* src = wswz + ((size_t)(kc * 12 + nt) * 64 + l) * 8;
            async16(src, bb + nt * 1024 + l * 16);
        }
    };

    int c0 = (quad & 1) * 2, hh = quad >> 1;           // A consumption coords

    stage(0, 0);
    for (int kc = 0; kc < 32; kc++) {
        __syncthreads();                       // vmcnt drain -> stage(kc) visible
        if (kc < 31) stage(kc + 1, (kc + 1) & 1);

        const char* ab = &lds[kc & 1][0];
        const char* bb = &lds[kc & 1][16 * 1024];

        short8 af[2];
#pragma unroll
        for (int r = 0; r < 2; r++) {
            int rt = 2 * w + r;
            const char* ap = ab + rt * 2048 + hh * 1024 + (c0 * 16 + m) * 16;
            float4 a0 = *(const float4*)(ap);          // floats quad*8 .. +4
            float4 a1 = *(const float4*)(ap + 256);    // floats quad*8+4 .. +4
            union { unsigned u[4]; short8 s; } cc;
            cc.u[0] = cvt_pk_bf16(a0.x, a0.y);
            cc.u[1] = cvt_pk_bf16(a0.z, a0.w);
            cc.u[2] = cvt_pk_bf16(a1.x, a1.y);
            cc.u[3] = cvt_pk_bf16(a1.z, a1.w);
            af[r] = cc.s;
        }
#pragma unroll
        for (int nt = 0; nt < 12; nt++) {
            short8 bf = *(const short8*)(bb + nt * 1024 + l * 16);
            acc[0][nt] = __builtin_amdgcn_mfma_f32_16x16x32_bf16(af[0], bf, acc[0][nt], 0, 0, 0);
            acc[1][nt] = __builtin_amdgcn_mfma_f32_16x16x32_bf16(af[1], bf, acc[1][nt], 0, 0, 0);
        }
    }

    // Epilogue. C/D layout: row=(lane>>4)*4+reg, col=lane&15.
#pragma unroll
    for (int r = 0; r < 2; r++) {
        int rt = 2 * w + r;
#pragma unroll
        for (int reg = 0; reg < 4; reg++) {
            int g = r0 + rt * 16 + quad * 4 + reg;
            int b = g >> 11, t = g & (Tn - 1);
#pragma unroll
            for (int nt = 0; nt < 4; nt++)                 // q: cols 0..63
                qb[(size_t)g * HSn + nt * 16 + m] = f2bf(acc[r][nt][reg]);
#pragma unroll
            for (int nt = 0; nt < 4; nt++)                 // k: cols 64..127
                kb[(size_t)g * HSn + nt * 16 + m] = f2bf(acc[r][4 + nt][reg]);
#pragma unroll
            for (int nt = 0; nt < 4; nt++)                 // v (transposed)
                vt[((size_t)b * HSn + nt * 16 + m) * Tn + t] = f2bf(acc[r][8 + nt][reg]);
        }
    }
}

// ---------------------------------------------------------------------------
// Kernel 3: causal attention, rewritten this round.
//
// Structure: grid 1024 = (qtile, batch), ONE q-tile (64 rows) per block,
// 4 blocks/CU (LDS exactly 40KB: 2x8KB K + 2x8KB V + 8KB P).  Batch is the
// fastest-varying blockIdx component -> all 32 blocks of batch b land on
// XCD b%8 (round-robin dispatch), so the 16x KV re-read is L2-served
// (4 batches x 512KB = 2MB < 4MB per-XCD L2).  qt chosen per rank so every
// CU's 4 resident blocks sum to 66 tile-units: {d, 15-d, 16+d, 31-d}.
//
// SWAPPED QK^T: s = mfma(A=K, B=Q) -> S^T in C-layout, i.e. lane (quad,m)
// holds S[q = m][kk = 16nt+4*quad+reg].  A/B frags have identical lane->data
// maps, so operand swap costs nothing.  Benefits:
//  - softmax row-sum is a per-lane scalar (2 shfl_xor at the end);
//  - P packs in-register via v_cvt_pk_bf16_f32 (kk pairs are reg-adjacent);
//  - P relayout to PV-A-layout is 8 ds_write_b32 + 2 ds_read_b128 (was
//    16 ds_write_b16 @4-way conflict + 2 reads).  pbuf row = q (m), 32 u32
//    words = kk pairs; 16B-chunk index XOR-swizzled with (m&7):
//    writes <=2-way (free), b128 reads conflict-free (each consecutive
//    8-lane group covers 8 distinct chunks).
// ---------------------------------------------------------------------------
__global__ __launch_bounds__(256, 4) void attn(const short* __restrict__ qb,
                                               const short* __restrict__ kb,
                                               const short* __restrict__ vt,
                                               float* __restrict__ out) {
    __shared__ __align__(16) short kbuf[2][64 * 64];       // 2 x 8KB
    __shared__ __align__(16) short vbuf[2][64 * 64];       // 2 x 8KB
    __shared__ __align__(16) unsigned pbuf[4][16][32];     // 8KB, per-wave rows=q

    int tid = threadIdx.x;
    int w = tid >> 6, l = tid & 63;
    int quad = l >> 4, m = l & 15;

    int bid = blockIdx.x;
    int b = bid & 31;                      // batch fastest -> XCD pinning
    int rank = bid >> 5;                   // 0..31
    int a = rank >> 3, d = rank & 7;
    int qt = (a & 1) ? (16 * (a >> 1) + 15 - d) : (16 * (a >> 1) + d);

    const short* kbbase = kb + (size_t)b * Tn * HSn;
    const short* vtbase = vt + (size_t)b * HSn * Tn;
    const float sl2e = 0.045084220027780106f;          // log2(e)/32

    // stage K/V tile j into buffer s (wave w's share: 2+2 instrs)
    int srow8 = l >> 3;                                // 0..7
    int schunk = l & 7;                                // 16B chunk
    auto stageKV = [&](int j, int s) {
#pragma unroll
        for (int i = 0; i < 2; i++) {
            int r = w * 16 + i * 8 + srow8;            // tile row 0..63
            int c = schunk ^ (r & 7);                  // XOR-swizzled src chunk
            async16(kbbase + ((size_t)(j * 64 + r)) * HSn + c * 8,
                    (char*)&kbuf[s][(w * 16 + i * 8) * 64] + l * 16);
            async16(vtbase + (size_t)r * Tn + j * 64 + c * 8,
                    (char*)&vbuf[s][(w * 16 + i * 8) * 64] + l * 16);
        }
    };

    int r0 = qt * 64 + w * 16;                         // wave's first q row
    int qloc = w * 16 + m;                             // this lane's q row (local)

    size_t qoff = ((size_t)b * Tn + r0 + m) * HSn;
    short8 qf0 = *(const short8*)(qb + qoff + quad * 8);
    short8 qf1 = *(const short8*)(qb + qoff + 32 + quad * 8);

    floatx4 o[4];
#pragma unroll
    for (int i = 0; i < 4; i++) o[i] = (floatx4)(0.0f);
    float ps = 0.0f;

    int swz = m & 7;

    stageKV(0, 0);
    for (int j = 0; j <= qt; j++) {
        __syncthreads();                           // stage(j) visible; buf j-1 free
        if (j < qt) stageKV(j + 1, (j + 1) & 1);

        const short* kt = &kbuf[j & 1][0];
        const short* vv = &vbuf[j & 1][0];

        // ---- S^T = K Q^T  (A=K-frag, B=Q-frag; same reads as before) ----
        floatx4 s[4];
#pragma unroll
        for (int i = 0; i < 4; i++) s[i] = (floatx4)(0.0f);
        __builtin_amdgcn_s_setprio(1);
#pragma unroll
        for (int kc = 0; kc < 2; kc++) {
            short8 aq = kc ? qf1 : qf0;
#pragma unroll
            for (int nt = 0; nt < 4; nt++) {
                short8 bk = *(const short8*)(kt + (nt * 16 + m) * 64 +
                                             ((kc * 4 + quad) ^ swz) * 8);
                s[nt] = __builtin_amdgcn_mfma_f32_16x16x32_bf16(bk, aq, s[nt], 0, 0, 0);
            }
        }
        __builtin_amdgcn_s_setprio(0);

        // ---- P = exp2(s*scale) (+ causal mask on diagonal tile) ----
        // lane (quad,m): S[q = qloc][kk = 16nt+4quad+reg]
        if (j == qt) {
#pragma unroll
            for (int nt = 0; nt < 4; nt++)
#pragma unroll
                for (int reg = 0; reg < 4; reg++) {
                    float pv = EXP2F(s[nt][reg] * sl2e);
                    pv = (nt * 16 + quad * 4 + reg > qloc) ? 0.0f : pv;
                    s[nt][reg] = pv;
                    ps += pv;
                }
        } else {
#pragma unroll
            for (int nt = 0; nt < 4; nt++)
#pragma unroll
                for (int reg = 0; reg < 4; reg++) {
                    float pv = EXP2F(s[nt][reg] * sl2e);
                    s[nt][reg] = pv;
                    ps += pv;
                }
        }

        // ---- pack P to bf16x2 and scatter to A-layout LDS (swizzled) ----
        asm volatile("" ::: "memory");
#pragma unroll
        for (int nt = 0; nt < 4; nt++)
#pragma unroll
            for (int h = 0; h < 2; h++) {
                unsigned u = cvt_pk_bf16(s[nt][2 * h], s[nt][2 * h + 1]);
                // logical u32 word = 8nt+2quad+h; chunk = 2nt+(quad>>1),
                // slot = 2(quad&1)+h; chunk XOR-swizzled with (m&7).
                pbuf[w][m][(((2 * nt + (quad >> 1)) ^ swz) << 2) +
                           2 * (quad & 1) + h] = u;
            }
        asm volatile("" ::: "memory");
        const unsigned* prow = &pbuf[w][m][0];
        short8 ap0 = *(const short8*)(prow + ((quad ^ swz) << 2));        // kk 0..31
        short8 ap1 = *(const short8*)(prow + (((4 + quad) ^ swz) << 2));  // kk 32..63
        asm volatile("" ::: "memory");

        // ---- O += P V ----
        __builtin_amdgcn_s_setprio(1);
#pragma unroll
        for (int nt = 0; nt < 4; nt++) {
            short8 bv0 = *(const short8*)(vv + (nt * 16 + m) * 64 + ((0 + quad) ^ swz) * 8);
            o[nt] = __builtin_amdgcn_mfma_f32_16x16x32_bf16(ap0, bv0, o[nt], 0, 0, 0);
        }
#pragma unroll
        for (int nt = 0; nt < 4; nt++) {
            short8 bv1 = *(const short8*)(vv + (nt * 16 + m) * 64 + ((4 + quad) ^ swz) * 8);
            o[nt] = __builtin_amdgcn_mfma_f32_16x16x32_bf16(ap1, bv1, o[nt], 0, 0, 0);
        }
        __builtin_amdgcn_s_setprio(0);
    }

    // ---- epilogue ----
    // ps currently: partial sum over this lane's kk subset for q = qloc.
    // Combine the 4 quads holding the same q row:
    ps += __shfl_xor(ps, 16, 64);
    ps += __shfl_xor(ps, 32, 64);
    // Output C-layout: lane (quad,m) holds O[q = r0+quad*4+reg][h = nt*16+m];
    // fetch the matching denominator from lane (quad*4+reg) (quad-0 lanes).
#pragma unroll
    for (int reg = 0; reg < 4; reg++) {
        float den = __shfl(ps, quad * 4 + reg, 64);
        float inv = 1.0f / den;
        int g = r0 + quad * 4 + reg;
#pragma unroll
        for (int nt = 0; nt < 4; nt++)
            out[((size_t)b * Tn + g) * HSn + nt * 16 + m] = o[nt][reg] * inv;
    }
}

// ---------------------------------------------------------------------------
extern "C" void kernel_launch(void* const* d_in, const int* in_sizes, int n_in,
                              void* d_out, int out_size, void* d_ws, size_t ws_size,
                              hipStream_t stream) {
    const float* x  = (const float*)d_in[0];
    const float* Wk = (const float*)d_in[1];
    const float* Wq = (const float*)d_in[2];
    const float* Wv = (const float*)d_in[3];
    float* out = (float*)d_out;

    char* ws = (char*)d_ws;
    short* wswz = (short*)ws;                           // 384 KB
    short* qb   = (short*)(ws + (1 << 19));             // 8 MB bf16 [B,T,64]
    short* kb   = (short*)(ws + (1 << 19) + (8 << 20)); // 8 MB bf16 [B,T,64]
    short* vt   = (short*)(ws + (1 << 19) + (16 << 20));// 8 MB bf16 [B,64,T]

    swz_w<<<dim3(768), dim3(256), 0, stream>>>(Wk, Wq, Wv, wswz);
    qkv_gemm<<<dim3(512), dim3(256), 0, stream>>>(x, wswz, qb, kb, vt);
    attn<<<dim3(1024), dim3(256), 0, stream>>>(qb, kb, vt, out);
}